// Round 1
// 263.059 us; speedup vs baseline: 1.0313x; 1.0313x over previous
//
#include <hip/hip_runtime.h>

// Fused 3-layer GCN (GS=7, H=144) + pool + fc, B=65536.  Round 12.
// R11 (215 us) was stall-bound: VALUBusy 46% + MfmaUtil 21%, Occupancy 32%
// (= 3 waves/SIMD; waves 2/3 hold 6 floatx16 accs = 96 regs + ~72 VGPR ~ 168,
// exactly the 512/3 cap). R12 shrinks per-wave state to raise occupancy:
//   NI 8->4 (28 rows): SINGLE m-tile -> accs 96 -> 40 regs worst-wave.
//   Tail tile n=128..143 via mfma_f32_16x16x32_f16 (4 m-tiles of 16, floatx4
//     accs on waves 2/3, K padded to 160 with zero weights) — also ~10% less
//     MFMA work than the old 32-wide padded tile.
//   LDS 53 -> ~26 KB; __launch_bounds__(256,5) -> target 5-6 blocks/CU
//     (20-24 waves/CU vs 12).
// Per-graph premix/epilogue VALU work unchanged; per-thread serial work halves.
// NaN-safety for zero-weight K/N padding: cols 16..31 (layer-0 16x16 reads),
// cols 144..151 and a 16-half tail pad are zeroed once before layer 0.
// Algorithm (verified R7-R11): Xn=nA@x, Xi=iA@x (cooperative premix to LDS);
//   x_new = 0.5*(relu(Xn@W1) + relu(Xi@W2)) as MFMA epilogue.
// Main wt layout (d_ws): [l][p][nt0..3][ks0..8] frags of 512 halfs,
//   n=nt*32+(lane&31) (<128), k=ks*16+(lane>>5)*8+j8.
// Tail wt layout: [l][p][ks32 0..4] frags of 512 halfs,
//   n=128+(lane&15), k=ks32*32+(lane>>4)*8+j8 (zero for k>=K).
// MFMA: A[n][k]=Wt, B[k][m]=Xmix -> D[n][m];
// 32x32 C/D: col=lane&31 (=m), row=(reg&3)+8*(reg>>2)+4*(lane>>5) (=n).
// 16x16 C/D: col=lane&15 (=m), row=(lane>>4)*4+reg (=n-128).

typedef _Float16 half8   __attribute__((ext_vector_type(8)));
typedef _Float16 half4_t __attribute__((ext_vector_type(4)));
typedef float    floatx16 __attribute__((ext_vector_type(16)));
typedef float    floatx4  __attribute__((ext_vector_type(4)));

constexpr int GS = 7;
constexpr int NI = 4;                 // graphs per block
constexpr int MROWS = NI * GS;        // 28
constexpr int H = 144;
constexpr int T4OFF   = 2 * 4 * 9 * 512;        // 36864 halfs: main frags/layer
constexpr int LSTRIDE = T4OFF + 2 * 5 * 512;    // 41984 halfs per layer
constexpr int WT_HALFS = 3 * LSTRIDE;           // 125952
constexpr int MAIN_T = 3 * 2 * 4 * 9 * 64;      // 13824 prep threads (blocks 0..53)
constexpr int T4_T   = 3 * 2 * 5 * 64;          // 1920  prep threads (blocks 54..61)
constexpr int XROW   = 152;                     // LDS row stride (halfs)

static __device__ inline half8 bc(_Float16 v) {
    half8 h = {v, v, v, v, v, v, v, v};
    return h;
}

// ---------------- prologue: weights -> fragment-linear fp16, g = fc2 @ fc1 ----------------
__global__ void prep_kernel(const float* __restrict__ w10, const float* __restrict__ w20,
                            const float* __restrict__ w11, const float* __restrict__ w21,
                            const float* __restrict__ w12, const float* __restrict__ w22,
                            const float* __restrict__ fc1, const float* __restrict__ fc2,
                            _Float16* __restrict__ wt, float* __restrict__ g)
{
    if (blockIdx.x == 62) {             // g = fc2 @ fc1 (both linear, no act)
        const int j = threadIdx.x;
        if (j < H) {
            float s = 0.f;
            for (int o = 0; o < 128; ++o) s = fmaf(fc2[o], fc1[o * H + j], s);
            g[j] = s;
        }
        return;
    }
    const int t = blockIdx.x * 256 + threadIdx.x;
    if (t < MAIN_T) {
        const int l    = t / 4608;          // 4608 = 72 frags * 64 lanes
        const int r    = t - l * 4608;
        const int frag = r >> 6;            // 0..71
        const int lane = r & 63;
        const int p    = frag / 36;         // 0 -> W1, 1 -> W2
        const int rem  = frag - p * 36;
        const int nt   = rem / 9;           // 0..3
        const int ks   = rem - nt * 9;      // 0..8
        const int n    = nt * 32 + (lane & 31);       // 0..127, always valid
        const int k0   = ks * 16 + (lane >> 5) * 8;
        const float* W = (l == 0) ? (p ? w20 : w10)
                       : (l == 1) ? (p ? w21 : w11)
                                  : (p ? w22 : w12);
        const int K = (l == 0) ? 5 : H;
        half8 h = bc((_Float16)0);
        #pragma unroll
        for (int j = 0; j < 8; ++j) {
            const int k = k0 + j;
            if (k < K) h[j] = (_Float16)W[k * H + n];   // lanes coalesce over n
        }
        *(half8*)(wt + (size_t)l * LSTRIDE + (size_t)((p * 4 + nt) * 9 + ks) * 512
                     + (size_t)lane * 8) = h;
    } else {
        const int t2 = t - MAIN_T;
        if (t2 >= T4_T) return;
        const int l    = t2 / 640;          // 640 = 10 frags * 64 lanes
        const int r    = t2 - l * 640;
        const int frag = r >> 6;            // 0..9
        const int lane = r & 63;
        const int p    = frag / 5;
        const int ks   = frag - p * 5;      // 32-wide K step, 0..4
        const int n    = 128 + (lane & 15); // 128..143, valid
        const int k0   = ks * 32 + (lane >> 4) * 8;
        const float* W = (l == 0) ? (p ? w20 : w10)
                       : (l == 1) ? (p ? w21 : w11)
                                  : (p ? w22 : w12);
        const int K = (l == 0) ? 5 : H;
        half8 h = bc((_Float16)0);
        #pragma unroll
        for (int j = 0; j < 8; ++j) {
            const int k = k0 + j;           // up to 159: zero-padded
            if (k < K) h[j] = (_Float16)W[k * H + n];
        }
        *(half8*)(wt + (size_t)l * LSTRIDE + T4OFF + (size_t)(p * 5 + ks) * 512
                     + (size_t)lane * 8) = h;
    }
}

// ---- one full layer: cooperative premix, single-m GEMM + 16x16 tail, epilogue ----
// Called uniformly by all 256 threads; barriers are workgroup-uniform.
template<int NK, int CB>
static __device__ __forceinline__ void layer_pass(const _Float16* __restrict__ wl,
                                                  const int tid, const int lane, const int wv,
                                                  _Float16 (*sX)[XROW],
                                                  _Float16 (*sXn)[XROW], _Float16 (*sXi)[XROW],
                                                  const _Float16 (*sAh)[2][GS][8])
{
    // ---- cooperative premix: Xn = nA@x, Xi = iA@x (once per block) ----
    for (int u = tid; u < MROWS * CB; u += 256) {
        const int row = u / CB, cb = u - row * CB;
        const int item = row / GS, rr = row - item * GS;
        const int c0 = cb * 8;
        const half8 aN = *(const half8*)&sAh[item][0][rr][0];
        const half8 aI = *(const half8*)&sAh[item][1][rr][0];
        half8 an = bc((_Float16)0), ai = bc((_Float16)0);
        #pragma unroll
        for (int j = 0; j < GS; ++j) {
            const half8 xj = *(const half8*)&sX[item * GS + j][c0];
            an += bc(aN[j]) * xj;
            ai += bc(aI[j]) * xj;
        }
        *(half8*)&sXn[row][c0] = an;
        *(half8*)&sXi[row][c0] = ai;
    }
    __syncthreads();   // B1: Xn/Xi ready; all reads of old sX complete

    // ---- wave-owned GEMM: wave wv owns main n-tile wv (cols wv*32..wv*32+31);
    //      waves 2,3 add the 16-col tail (cols 128..143) as 16x16x32, mt = wv&1.
    const int  nt    = wv;                 // wave-uniform
    const bool extra = (wv >= 2);
    const int  mt    = wv & 1;             // tail m-tile: wave2 -> rows 0..15, wave3 -> 16..27
    const int  khi   = (lane >> 5) * 8;
    const int  r0    = lane & 31;
    const int  r0c   = (r0 < MROWS) ? r0 : (MROWS - 1);    // clamp B-row reads
    const int  rr4r  = mt * 16 + (lane & 15);
    const int  rr4   = (rr4r < MROWS) ? rr4r : (MROWS - 1);

    floatx16 a1, a2;     // main accs (W1, W2 paths)
    floatx4  e1, e2;     // tail accs
    #pragma unroll
    for (int i = 0; i < 16; ++i) { a1[i] = 0.f; a2[i] = 0.f; }
    #pragma unroll
    for (int i = 0; i < 4; ++i)  { e1[i] = 0.f; e2[i] = 0.f; }

    #pragma unroll
    for (int ks = 0; ks < NK; ++ks) {
        const int c = ks * 16 + khi;
        const half8 bn = *(const half8*)&sXn[r0c][c];
        const half8 bi = *(const half8*)&sXi[r0c][c];
        const _Float16* f1 = wl + (size_t)((nt * 9 + ks) * 512) + (size_t)lane * 8;
        const half8 A1 = *(const half8*)f1;               // p=0 (W1)
        const half8 A2 = *(const half8*)(f1 + 36 * 512);  // p=1 (W2)
        a1 = __builtin_amdgcn_mfma_f32_32x32x16_f16(A1, bn, a1, 0, 0, 0);
        a2 = __builtin_amdgcn_mfma_f32_32x32x16_f16(A2, bi, a2, 0, 0, 0);
        if (extra && !(ks & 1)) {          // 32-wide tail K step every other ks
            const int t4 = ks >> 1;        // 0..4 (NK=9) or 0 (NK=1)
            const int k4 = t4 * 32 + (lane >> 4) * 8;
            const half8 b4n = *(const half8*)&sXn[rr4][k4];
            const half8 b4i = *(const half8*)&sXi[rr4][k4];
            const _Float16* f4 = wl + T4OFF + (size_t)(t4 * 512) + (size_t)lane * 8;
            const half8 E1 = *(const half8*)f4;               // p=0
            const half8 E2 = *(const half8*)(f4 + 5 * 512);   // p=1
            e1 = __builtin_amdgcn_mfma_f32_16x16x32_f16(E1, b4n, e1, 0, 0, 0);
            e2 = __builtin_amdgcn_mfma_f32_16x16x32_f16(E2, b4i, e2, 0, 0, 0);
        }
    }

    // ---- epilogue: x_new = 0.5*(relu(P1)+relu(P2)) straight to sX ----
    if (r0 < MROWS) {
        #pragma unroll
        for (int q = 0; q < 4; ++q) {
            const int n0 = nt * 32 + 4 * (lane >> 5) + 8 * q;
            half4_t h0;
            #pragma unroll
            for (int i = 0; i < 4; ++i) {
                float v1 = a1[4 * q + i]; v1 = v1 > 0.f ? v1 : 0.f;
                float v2 = a2[4 * q + i]; v2 = v2 > 0.f ? v2 : 0.f;
                h0[i] = (_Float16)(0.5f * (v1 + v2));
            }
            *(half4_t*)&sX[r0][n0] = h0;
        }
    }
    if (extra && rr4r < MROWS) {           // tail cols 128..143
        const int n0 = 128 + (lane >> 4) * 4;
        half4_t h;
        #pragma unroll
        for (int i = 0; i < 4; ++i) {
            float v1 = e1[i]; v1 = v1 > 0.f ? v1 : 0.f;
            float v2 = e2[i]; v2 = v2 > 0.f ? v2 : 0.f;
            h[i] = (_Float16)(0.5f * (v1 + v2));
        }
        *(half4_t*)&sX[rr4r][n0] = h;
    }
    __syncthreads();   // B2: x_new visible for next premix / pool
}

__global__ __launch_bounds__(256, 5)
void gcn_mfma(const float* __restrict__ ops, const float* __restrict__ adj,
              const float* __restrict__ nv,
              const _Float16* __restrict__ wt, const float* __restrict__ gw,
              float* __restrict__ out)
{
    // one backing array so the 16B over-read of row 27 at k=152..159 stays
    // inside block LDS and lands on the zeroed tail pad.
    __shared__ __align__(16) _Float16 sMem[3 * MROWS * XROW + 16];   // 25568 B
    __shared__ __align__(16) _Float16 sAh[NI][2][GS][8];             //   896 B

    _Float16 (*sX)[XROW]  = (_Float16(*)[XROW])&sMem[0];
    _Float16 (*sXn)[XROW] = (_Float16(*)[XROW])&sMem[MROWS * XROW];
    _Float16 (*sXi)[XROW] = (_Float16(*)[XROW])&sMem[2 * MROWS * XROW];

    float (*adjd)[GS][GS] = (float(*)[GS][GS])&sXn[0][0];   // prologue-only scratch

    const int tid  = threadIdx.x;
    const int lane = tid & 63;
    const int wv   = tid >> 6;
    const int ibase = blockIdx.x * NI;

    // ---------------- per-block prologue: stage X (fp16), adjacency matrices ----------------
    if (tid < MROWS) {
        const int item = tid / GS, r = tid % GS;
        const float* orow = ops + ((size_t)(ibase + item) * GS + r) * 5;
        half8 h = bc((_Float16)0);
        h[0] = (_Float16)orow[0]; h[1] = (_Float16)orow[1]; h[2] = (_Float16)orow[2];
        h[3] = (_Float16)orow[3]; h[4] = (_Float16)orow[4];
        *(half8*)&sX[tid][0] = h;
        *(half8*)&sX[tid][8] = bc((_Float16)0);   // layer-0 K pad (k=5..15)

        const float* arow = adj + ((size_t)(ibase + item) * GS + r) * GS;
        float a[GS]; float sm = 0.f;
        #pragma unroll
        for (int c = 0; c < GS; ++c) { a[c] = arow[c] + (c == r ? 1.f : 0.f); sm += a[c]; }
        const float is = 1.f / sm;
        #pragma unroll
        for (int c = 0; c < GS; ++c) {
            const float v = a[c] * is;
            adjd[item][r][c] = v;
            sAh[item][0][r][c] = (_Float16)v;
        }
        sAh[item][0][r][7] = (_Float16)0.f;
    }
    __syncthreads();
    if (tid < MROWS) {    // inv_norm_adj = row_normalize(adj_d^T)
        const int item = tid / GS, r = tid % GS;
        float v[GS]; float sm = 0.f;
        #pragma unroll
        for (int k = 0; k < GS; ++k) { v[k] = adjd[item][k][r]; sm += v[k]; }
        const float is = 1.f / sm;
        #pragma unroll
        for (int k = 0; k < GS; ++k) sAh[item][1][r][k] = (_Float16)(v[k] * is);
        sAh[item][1][r][7] = (_Float16)0.f;
    }
    __syncthreads();

    // zero stale/pad LDS that zero-weight MFMA K/N padding will read
    // (adjd scratch is dead now; these writes are covered by layer-0's B1):
    //   cols 16..31: layer-0 tail reads k=0..31 while premix only writes 0..15
    //   cols 144..151: K=144..151 pad for the k=128..159 tail step
    //   tail 16 halfs after sXi: row-27 over-read at k=152..159
    if (tid < MROWS) {
        const half8 z = bc((_Float16)0);
        *(half8*)&sXn[tid][16]  = z; *(half8*)&sXn[tid][24]  = z;
        *(half8*)&sXi[tid][16]  = z; *(half8*)&sXi[tid][24]  = z;
        *(half8*)&sXn[tid][144] = z;
        *(half8*)&sXi[tid][144] = z;
    }
    if (tid == 32) {
        const half8 z = bc((_Float16)0);
        *(half8*)&sMem[3 * MROWS * XROW]     = z;
        *(half8*)&sMem[3 * MROWS * XROW + 8] = z;
    }

    // ==================== 3 layers ====================
    layer_pass<1, 2>(wt,                        tid, lane, wv, sX, sXn, sXi, sAh);
    layer_pass<9, 18>(wt + (size_t)1 * LSTRIDE, tid, lane, wv, sX, sXn, sXi, sAh);
    layer_pass<9, 18>(wt + (size_t)2 * LSTRIDE, tid, lane, wv, sX, sXn, sXi, sAh);

    // ==================== pool + (fc2@fc1) dot ====================
    if (tid < NI * 16) {
        const int item = tid >> 4, part = tid & 15;
        float s = 0.f;
        #pragma unroll
        for (int c = 0; c < 9; ++c) {
            const int j = part * 9 + c;
            const float gj = gw[j];
            #pragma unroll
            for (int i = 0; i < GS; ++i)
                s = fmaf((float)sX[item * GS + i][j], gj, s);
        }
        s += __shfl_xor(s, 1);
        s += __shfl_xor(s, 2);
        s += __shfl_xor(s, 4);
        s += __shfl_xor(s, 8);
        if (part == 0) out[ibase + item] = s / nv[ibase + item];
    }
}

extern "C" void kernel_launch(void* const* d_in, const int* in_sizes, int n_in,
                              void* d_out, int out_size, void* d_ws, size_t ws_size,
                              hipStream_t stream) {
    const float* ops = (const float*)d_in[0];
    const float* adj = (const float*)d_in[1];
    const float* nv  = (const float*)d_in[2];
    const float* w10 = (const float*)d_in[3];
    const float* w20 = (const float*)d_in[4];
    const float* w11 = (const float*)d_in[5];
    const float* w21 = (const float*)d_in[6];
    const float* w12 = (const float*)d_in[7];
    const float* w22 = (const float*)d_in[8];
    const float* fc1 = (const float*)d_in[9];
    const float* fc2 = (const float*)d_in[10];

    _Float16* wt = (_Float16*)d_ws;                              // 251904 B
    float*    g  = (float*)((char*)d_ws + (size_t)WT_HALFS * 2); // 576 B

    prep_kernel<<<63, 256, 0, stream>>>(w10, w20, w11, w21, w12, w22,
                                        fc1, fc2, wt, g);
    gcn_mfma<<<65536 / NI, 256, 0, stream>>>(ops, adj, nv, wt, g, (float*)d_out);
}